// Round 4
// baseline (3769.809 us; speedup 1.0000x reference)
//
#include <hip/hip_runtime.h>
#include <math.h>

#define H 200
#define TT 4
#define BB 64
#define MM 1000
#define NEGV (-1e30f)

static const int ROWS = BB * MM;   // 64000
#define KA 416                     // 400 padded to x32
#define KB 224                     // 200 padded to x32
#define NPAD 896                   // 800 padded to 7*128
#define NSLICE 28                  // 14 per GEMM family
#define LSTR 40                    // LDS row stride in ushorts (80B) - bank-conflict pad

typedef __attribute__((ext_vector_type(8))) short short8;
typedef __attribute__((ext_vector_type(4))) float f32x4;

// truncation hi/lo split: (hi+lo) rel err ~2^-16
__device__ __forceinline__ void split2(float x, unsigned short& h, unsigned short& l) {
  unsigned u = __float_as_uint(x);
  h = (unsigned short)(u >> 16);
  float res = x - __uint_as_float(u & 0xffff0000u);
  l = (unsigned short)(__float_as_uint(res) >> 16);
}

// ---------------------------------------------------------------- init
__global__ __launch_bounds__(256) void k_init(const int* __restrict__ dmask,
    int* st_s, int* st_e, int* ms, int* me,
    float* h, float* c, float* out) {
  int b = blockIdx.x, t = threadIdx.x;
  __shared__ int red[256];
  int sum = 0;
  for (int m = t; m < MM; m += 256) sum += dmask[b * MM + m];
  red[t] = sum; __syncthreads();
  for (int s = 128; s > 0; s >>= 1) { if (t < s) red[t] += red[t + s]; __syncthreads(); }
  if (t == 0) { st_s[b] = 0; st_e[b] = red[0] - 1; ms[b] = 1; me[b] = 1; }
  for (int i = t; i < H; i += 256) { h[b * H + i] = 0.f; c[b * H + i] = 0.f; }
  if (b == 0 && t == 0) out[0] = 0.f;
}

// ---------------------------------------------------------------- split fp32 -> bf16 hi/lo
// rows >= Nsrc or cols >= Ksrc zeroed. grid = Npad blocks.
__global__ __launch_bounds__(256) void k_split(const float* __restrict__ src, int srcld,
    int Ksrc, int Nsrc,
    unsigned short* __restrict__ hi, unsigned short* __restrict__ lo, int Kpad) {
  int r = blockIdx.x;
  for (int k = threadIdx.x; k < Kpad; k += 256) {
    unsigned short h = 0, l = 0;
    if (r < Nsrc && k < Ksrc) split2(src[(size_t)r * srcld + k], h, l);
    hi[(size_t)r * Kpad + k] = h;
    lo[(size_t)r * Kpad + k] = l;
  }
}

// ---------------------------------------------------------------- LSTM + r(tag s) + rcorr
__global__ __launch_bounds__(1024) void k_lstm_r(
    const float* __restrict__ U, const int* __restrict__ st_s, const int* __restrict__ st_e,
    float* __restrict__ h, float* __restrict__ c,
    const float* __restrict__ w_ih, const float* __restrict__ w_hh,
    const float* __restrict__ b_ih, const float* __restrict__ b_hh,
    const float* __restrict__ Wr, const float* __restrict__ W1, const float* __restrict__ b1,
    float* __restrict__ rcorr, float* __restrict__ ue) {
  int b = blockIdx.x, t = threadIdx.x;
  __shared__ float xc[1000];   // [h_new(200) | u_cat(800)]
  __shared__ float hold[H];
  __shared__ float g[800];
  __shared__ float r[H];
  int si = st_s[b], ei = st_e[b];
  const float* Us = U + ((size_t)b * MM + si) * 400;
  const float* Ue = U + ((size_t)b * MM + ei) * 400;
  if (t < 400) { xc[200 + t] = Us[t]; xc[600 + t] = Ue[t]; ue[b * 400 + t] = Ue[t]; }
  if (t >= 400 && t < 600) hold[t - 400] = h[b * H + (t - 400)];
  __syncthreads();
  if (t < 800) {
    float acc = b_ih[t] + b_hh[t];
    const float4* wi = (const float4*)(w_ih + (size_t)t * 800);
    const float* xv = &xc[200];
    for (int k = 0; k < 200; ++k) {
      float4 wv = wi[k];
      acc = fmaf(wv.x, xv[k * 4 + 0], acc); acc = fmaf(wv.y, xv[k * 4 + 1], acc);
      acc = fmaf(wv.z, xv[k * 4 + 2], acc); acc = fmaf(wv.w, xv[k * 4 + 3], acc);
    }
    const float4* wh = (const float4*)(w_hh + (size_t)t * H);
    for (int k = 0; k < 50; ++k) {
      float4 wv = wh[k];
      acc = fmaf(wv.x, hold[k * 4 + 0], acc); acc = fmaf(wv.y, hold[k * 4 + 1], acc);
      acc = fmaf(wv.z, hold[k * 4 + 2], acc); acc = fmaf(wv.w, hold[k * 4 + 3], acc);
    }
    g[t] = acc;
  }
  __syncthreads();
  if (t < H) {
    float ig = 1.f / (1.f + expf(-g[t]));
    float fg = 1.f / (1.f + expf(-g[H + t]));
    float gg = tanhf(g[2 * H + t]);
    float og = 1.f / (1.f + expf(-g[3 * H + t]));
    float cn = fg * c[b * H + t] + ig * gg;
    c[b * H + t] = cn;
    float hv = og * tanhf(cn);
    h[b * H + t] = hv;
    xc[t] = hv;
  }
  __syncthreads();
  if (t < H) {
    float acc = 0.f;
    const float4* wr = (const float4*)(Wr + (size_t)t * 1000);
    for (int k = 0; k < 250; ++k) {
      float4 wv = wr[k];
      acc = fmaf(wv.x, xc[k * 4 + 0], acc); acc = fmaf(wv.y, xc[k * 4 + 1], acc);
      acc = fmaf(wv.z, xc[k * 4 + 2], acc); acc = fmaf(wv.w, xc[k * 4 + 3], acc);
    }
    r[t] = tanhf(acc);
  }
  __syncthreads();
  if (t < NPAD) {
    float acc = 0.f;
    if (t < 800) {
      acc = b1[t];
      const float4* w1 = (const float4*)(W1 + (size_t)t * 600 + 400);
      for (int k = 0; k < 50; ++k) {
        float4 wv = w1[k];
        acc = fmaf(wv.x, r[k * 4 + 0], acc); acc = fmaf(wv.y, r[k * 4 + 1], acc);
        acc = fmaf(wv.z, r[k * 4 + 2], acc); acc = fmaf(wv.w, r[k * 4 + 3], acc);
      }
    }
    rcorr[b * NPAD + t] = acc;
  }
}

// ---------------------------------------------------------------- r(tag e) + rcorr
__global__ __launch_bounds__(1024) void k_re(
    const float* __restrict__ U, const int* __restrict__ st_s,
    const float* __restrict__ ue, const float* __restrict__ h,
    const float* __restrict__ Wr, const float* __restrict__ W1, const float* __restrict__ b1,
    float* __restrict__ rcorr) {
  int b = blockIdx.x, t = threadIdx.x;
  __shared__ float xc[1000];
  __shared__ float r[H];
  const float* Us = U + ((size_t)b * MM + st_s[b]) * 400;
  if (t < 200) xc[t] = h[b * H + t];
  if (t >= 200 && t < 600) xc[t] = Us[t - 200];
  if (t >= 600 && t < 1000) xc[t] = ue[b * 400 + (t - 600)];
  __syncthreads();
  if (t < H) {
    float acc = 0.f;
    const float4* wr = (const float4*)(Wr + (size_t)t * 1000);
    for (int k = 0; k < 250; ++k) {
      float4 wv = wr[k];
      acc = fmaf(wv.x, xc[k * 4 + 0], acc); acc = fmaf(wv.y, xc[k * 4 + 1], acc);
      acc = fmaf(wv.z, xc[k * 4 + 2], acc); acc = fmaf(wv.w, xc[k * 4 + 3], acc);
    }
    r[t] = tanhf(acc);
  }
  __syncthreads();
  if (t < NPAD) {
    float acc = 0.f;
    if (t < 800) {
      acc = b1[t];
      const float4* w1 = (const float4*)(W1 + (size_t)t * 600 + 400);
      for (int k = 0; k < 50; ++k) {
        float4 wv = w1[k];
        acc = fmaf(wv.x, r[k * 4 + 0], acc); acc = fmaf(wv.y, r[k * 4 + 1], acc);
        acc = fmaf(wv.z, r[k * 4 + 2], acc); acc = fmaf(wv.w, r[k * 4 + 3], acc);
      }
    }
    rcorr[b * NPAD + t] = acc;
  }
}

// ---------------------------------------------------------------- MFMA GEMM (split-bf16, 3-pass)
// grid = (NPAD/128, ROWS/128): x = N panel (A reused by 7 consecutive blocks), y = rows.
// PRESPLIT=0: A fp32 (lda,KsrcA), split in-register. PRESPLIT=1: A pre-split (stride Kpad).
// MODE 0 (m1): add rcorr[b][col], maxpool4 -> write m1 hi/lo bf16, alpha slices 0..13.
// MODE 1 (m2): add b2[col], maxpool4, no C write, alpha slices 14..27.
template <int MODE, int PRESPLIT>
__global__ __launch_bounds__(256) void k_mgemm(
    const float* __restrict__ Af, int lda, int KsrcA,
    const unsigned short* __restrict__ Ah, const unsigned short* __restrict__ Al,
    const unsigned short* __restrict__ Bh, const unsigned short* __restrict__ Bl, int Kpad,
    const float* __restrict__ addv,
    unsigned short* __restrict__ Couth, unsigned short* __restrict__ Coutl,
    float* __restrict__ partial, const float* __restrict__ W12, int slice_base) {
  __shared__ unsigned short sAh[128 * LSTR], sAl[128 * LSTR];
  __shared__ unsigned short sBh[128 * LSTR], sBl[128 * LSTR];
  const int tid = threadIdx.x;
  const int lane = tid & 63, wave = tid >> 6;
  const int wm = wave >> 1, wn = wave & 1;
  const int n0 = blockIdx.x * 128, row0 = blockIdx.y * 128;
  const int lr = lane & 15, ls = lane >> 4;

  f32x4 acc[4][4];
#pragma unroll
  for (int i = 0; i < 4; ++i)
#pragma unroll
    for (int j = 0; j < 4; ++j) acc[i][j] = (f32x4){0.f, 0.f, 0.f, 0.f};

  const int srow = tid >> 1, shalf = tid & 1;
  const float* Afp = Af ? (Af + (size_t)(row0 + srow) * lda + shalf * 16) : nullptr;
  const unsigned short* Ahp = Ah ? (Ah + (size_t)(row0 + srow) * Kpad + shalf * 16) : nullptr;
  const unsigned short* Alp = Al ? (Al + (size_t)(row0 + srow) * Kpad + shalf * 16) : nullptr;
  const unsigned short* Bhp = Bh + (size_t)(n0 + srow) * Kpad + shalf * 16;
  const unsigned short* Blp = Bl + (size_t)(n0 + srow) * Kpad + shalf * 16;
  const int wo = srow * LSTR + shalf * 16;
  const int aoff = (wm * 64 + lr) * LSTR + ls * 8;
  const int boff = (wn * 64 + lr) * LSTR + ls * 8;

  short8 rah0, rah1, ral0, ral1, rbh0, rbh1, rbl0, rbl1;

  auto loadk = [&](int kt) {
    if (PRESPLIT) {
      rah0 = *(const short8*)(Ahp + kt * 32);
      rah1 = *(const short8*)(Ahp + kt * 32 + 8);
      ral0 = *(const short8*)(Alp + kt * 32);
      ral1 = *(const short8*)(Alp + kt * 32 + 8);
    } else {
      const int kk = kt * 32 + shalf * 16;
      float av[16];
#pragma unroll
      for (int q = 0; q < 4; ++q) {
        float4 v;
        if (kk + q * 4 + 4 <= KsrcA) v = *(const float4*)(Afp + kt * 32 + q * 4);
        else v = make_float4(0.f, 0.f, 0.f, 0.f);
        av[q * 4 + 0] = v.x; av[q * 4 + 1] = v.y;
        av[q * 4 + 2] = v.z; av[q * 4 + 3] = v.w;
      }
#pragma unroll
      for (int e = 0; e < 8; ++e) {
        unsigned short hh, ll;
        split2(av[e], hh, ll);     rah0[e] = (short)hh; ral0[e] = (short)ll;
        split2(av[8 + e], hh, ll); rah1[e] = (short)hh; ral1[e] = (short)ll;
      }
    }
    rbh0 = *(const short8*)(Bhp + kt * 32);
    rbh1 = *(const short8*)(Bhp + kt * 32 + 8);
    rbl0 = *(const short8*)(Blp + kt * 32);
    rbl1 = *(const short8*)(Blp + kt * 32 + 8);
  };

  const int nk = Kpad >> 5;
  loadk(0);
  for (int kt = 0; kt < nk; ++kt) {
    *(short8*)&sAh[wo] = rah0; *(short8*)&sAh[wo + 8] = rah1;
    *(short8*)&sAl[wo] = ral0; *(short8*)&sAl[wo + 8] = ral1;
    *(short8*)&sBh[wo] = rbh0; *(short8*)&sBh[wo + 8] = rbh1;
    *(short8*)&sBl[wo] = rbl0; *(short8*)&sBl[wo + 8] = rbl1;
    __syncthreads();
    if (kt + 1 < nk) loadk(kt + 1);   // VMEM latency hides under MFMA below

    short8 fa[4], fb[4];
#pragma unroll
    for (int i = 0; i < 4; ++i) fa[i] = *(const short8*)&sAh[aoff + i * 16 * LSTR];
#pragma unroll
    for (int j = 0; j < 4; ++j) fb[j] = *(const short8*)&sBh[boff + j * 16 * LSTR];
#pragma unroll
    for (int i = 0; i < 4; ++i)
#pragma unroll
      for (int j = 0; j < 4; ++j)
        acc[i][j] = __builtin_amdgcn_mfma_f32_16x16x32_bf16(fa[i], fb[j], acc[i][j], 0, 0, 0);
    short8 fc[4];
#pragma unroll
    for (int j = 0; j < 4; ++j) fc[j] = *(const short8*)&sBl[boff + j * 16 * LSTR];
#pragma unroll
    for (int i = 0; i < 4; ++i)
#pragma unroll
      for (int j = 0; j < 4; ++j)
        acc[i][j] = __builtin_amdgcn_mfma_f32_16x16x32_bf16(fa[i], fc[j], acc[i][j], 0, 0, 0);
#pragma unroll
    for (int i = 0; i < 4; ++i) fa[i] = *(const short8*)&sAl[aoff + i * 16 * LSTR];
#pragma unroll
    for (int i = 0; i < 4; ++i)
#pragma unroll
      for (int j = 0; j < 4; ++j)
        acc[i][j] = __builtin_amdgcn_mfma_f32_16x16x32_bf16(fa[i], fb[j], acc[i][j], 0, 0, 0);
    __syncthreads();
  }

  // ---------------- fused epilogue ----------------
  const int colb = n0 + wn * 64 + lr;
  const int rowb = row0 + wm * 64 + ls * 4;
  const int pmine = lane & 3;
  const int woff = (MODE == 0) ? 0 : 200;
  float w12j[4], addj[4];
#pragma unroll
  for (int j = 0; j < 4; ++j) {
    const int col = colb + j * 16;
    w12j[j] = (col < 800) ? W12[pmine * 400 + woff + (col >> 2)] : 0.f;
    if (MODE == 1) addj[j] = (col < 800) ? addv[col] : 0.f;
  }
  const int slice = slice_base + blockIdx.x * 2 + wn;
#pragma unroll
  for (int i = 0; i < 4; ++i) {
#pragma unroll
    for (int r = 0; r < 4; ++r) {
      const int row = rowb + i * 16 + r;
      float sp = 0.f;
#pragma unroll
      for (int j = 0; j < 4; ++j) {
        const int col = colb + j * 16;
        float v = acc[i][j][r];
        if (MODE == 0) {
          const unsigned bidx = (unsigned)row / 1000u;
          v += addv[bidx * NPAD + col];
        } else {
          v += addj[j];
        }
        v = fmaxf(v, __shfl_xor(v, 1));
        v = fmaxf(v, __shfl_xor(v, 2));
        if (MODE == 0 && (lane & 3) == 0) {
          unsigned short hh, ll;
          split2(v, hh, ll);
          Couth[(size_t)row * KB + (col >> 2)] = hh;
          Coutl[(size_t)row * KB + (col >> 2)] = ll;
        }
        sp = fmaf(v, w12j[j], sp);
      }
      sp += __shfl_xor(sp, 4);
      sp += __shfl_xor(sp, 8);
      if (lr < 4)
        partial[((size_t)row * NSLICE + slice) * 4 + lr] = sp;
    }
  }
}

// ---------------------------------------------------------------- alpha-reduce + argmax + lse
__global__ __launch_bounds__(256) void k_reduce(const float* __restrict__ partial,
    const float* __restrict__ b12, const int* __restrict__ dmask,
    const int* __restrict__ span, int tag,
    int* __restrict__ idx_out, float* __restrict__ atgt_out) {
  int b = blockIdx.x, t = threadIdx.x;
  __shared__ float vals[MM];
  __shared__ float rv[256];
  __shared__ int ri[256];
  float4 bb = *(const float4*)b12;
  float bestv = -3.4e38f; int besti = 0x7fffffff;
  for (int m = t; m < MM; m += 256) {
    const float4* pr = (const float4*)(partial + ((size_t)(b * MM + m)) * (NSLICE * 4));
    float4 a4 = bb;
#pragma unroll
    for (int s = 0; s < NSLICE; ++s) {
      float4 p4 = pr[s];
      a4.x += p4.x; a4.y += p4.y; a4.z += p4.z; a4.w += p4.w;
    }
    float v = fmaxf(fmaxf(a4.x, a4.y), fmaxf(a4.z, a4.w));
    if (!dmask[b * MM + m]) v += NEGV;
    vals[m] = v;
    if (v > bestv || (v == bestv && m < besti)) { bestv = v; besti = m; }
  }
  rv[t] = bestv; ri[t] = besti; __syncthreads();
  for (int s = 128; s > 0; s >>= 1) {
    if (t < s) {
      float v2 = rv[t + s]; int i2 = ri[t + s];
      if (v2 > rv[t] || (v2 == rv[t] && i2 < ri[t])) { rv[t] = v2; ri[t] = i2; }
    }
    __syncthreads();
  }
  float vmax = rv[0]; int vidx = ri[0];
  __syncthreads();
  float se = 0.f;
  for (int m = t; m < MM; m += 256) se += expf(vals[m] - vmax);
  rv[t] = se; __syncthreads();
  for (int s = 128; s > 0; s >>= 1) { if (t < s) rv[t] += rv[t + s]; __syncthreads(); }
  if (t == 0) {
    int tgt = span[b * 2 + tag];
    atgt_out[b] = vals[tgt] - vmax - logf(rv[0]);
    idx_out[b] = vidx;
  }
}

// ---------------------------------------------------------------- state update + loss
__global__ __launch_bounds__(64) void k_update(const int* __restrict__ idx_buf,
    const float* __restrict__ atgt, int* __restrict__ st, int* __restrict__ mstate,
    float* __restrict__ pout, float* __restrict__ loss, int first) {
  int b = threadIdx.x;
  int idx = idx_buf[b];
  int sold = st[b], msold = mstate[b];
  int snew = first ? idx : (msold ? idx : 0);
  int msnew = first ? 1 : ((snew != (msold ? sold : 0)) ? 1 : 0);
  st[b] = snew; mstate[b] = msnew;
  if (msnew) pout[b] = (float)snew;
  float asum = atgt[b];
  float csum = (float)msnew;
  for (int off = 32; off > 0; off >>= 1) {
    asum += __shfl_down(asum, off);
    csum += __shfl_down(csum, off);
  }
  if (b == 0) loss[0] += (-asum / (float)BB) * csum / (float)(BB * TT);
}

// ---------------------------------------------------------------- launch
extern "C" void kernel_launch(void* const* d_in, const int* in_sizes, int n_in,
                              void* d_out, int out_size, void* d_ws, size_t ws_size,
                              hipStream_t stream) {
  const float* U     = (const float*)d_in[0];
  const int*   dmask = (const int*)d_in[1];
  const int*   span  = (const int*)d_in[2];
  const float* w_ih  = (const float*)d_in[3];
  const float* w_hh  = (const float*)d_in[4];
  const float* b_ih  = (const float*)d_in[5];
  const float* b_hh  = (const float*)d_in[6];
  const float* Wr[2]  = {(const float*)d_in[7],  (const float*)d_in[14]};
  const float* W1[2]  = {(const float*)d_in[8],  (const float*)d_in[15]};
  const float* b1[2]  = {(const float*)d_in[9],  (const float*)d_in[16]};
  const float* W2[2]  = {(const float*)d_in[10], (const float*)d_in[17]};
  const float* b2[2]  = {(const float*)d_in[11], (const float*)d_in[18]};
  const float* W12[2] = {(const float*)d_in[12], (const float*)d_in[19]};
  const float* b12[2] = {(const float*)d_in[13], (const float*)d_in[20]};
  float* out = (float*)d_out;

  size_t off = 0;
  char* base = (char*)d_ws;
  auto alloc = [&](size_t n) {
    void* p = base + off;
    off += (n + 255) & ~(size_t)255;
    return p;
  };
  unsigned short* m1h = (unsigned short*)alloc((size_t)ROWS * KB * 2);  // 28.7 MB
  unsigned short* m1l = (unsigned short*)alloc((size_t)ROWS * KB * 2);  // 28.7 MB
  float* partial = (float*)alloc((size_t)ROWS * NSLICE * 4 * 4);        // 28.7 MB
  float* rcorr   = (float*)alloc((size_t)BB * NPAD * 4);
  float* ue      = (float*)alloc((size_t)BB * 400 * 4);
  float* hbuf    = (float*)alloc((size_t)BB * H * 4);
  float* cbuf    = (float*)alloc((size_t)BB * H * 4);
  float* atgt    = (float*)alloc((size_t)BB * 4);
  int* st_s = (int*)alloc(BB * 4);
  int* st_e = (int*)alloc(BB * 4);
  int* msb  = (int*)alloc(BB * 4);
  int* meb  = (int*)alloc(BB * 4);
  int* idxb = (int*)alloc(BB * 4);
  unsigned short *W1h[2], *W1l[2], *W2h[2], *W2l[2];
  for (int g = 0; g < 2; ++g) {
    W1h[g] = (unsigned short*)alloc((size_t)NPAD * KA * 2);
    W1l[g] = (unsigned short*)alloc((size_t)NPAD * KA * 2);
    W2h[g] = (unsigned short*)alloc((size_t)NPAD * KB * 2);
    W2l[g] = (unsigned short*)alloc((size_t)NPAD * KB * 2);
  }
  // tier B: pre-split U to bf16 hi/lo (saves in-loop fp32 split VALU + fetch)
  const size_t UHL_B = (size_t)ROWS * KA * 2;      // 53.2 MB each
  bool tierB = (ws_size >= off + 2 * UHL_B + 4096);
  unsigned short *Uh = nullptr, *Ul = nullptr;
  if (tierB) {
    Uh = (unsigned short*)alloc(UHL_B);
    Ul = (unsigned short*)alloc(UHL_B);
  }

  k_init<<<BB, 256, 0, stream>>>(dmask, st_s, st_e, msb, meb, hbuf, cbuf, out);
  for (int g = 0; g < 2; ++g) {
    k_split<<<NPAD, 256, 0, stream>>>(W1[g], 600, 400, 800, W1h[g], W1l[g], KA);
    k_split<<<NPAD, 256, 0, stream>>>(W2[g], 200, 200, 800, W2h[g], W2l[g], KB);
  }
  if (tierB)
    k_split<<<ROWS, 256, 0, stream>>>(U, 400, 400, ROWS, Uh, Ul, KA);

  dim3 gg(NPAD / 128, ROWS / 128);   // (7, 500): x = N-panels, consecutive blocks share A-panel
  for (int t = 0; t < TT; ++t) {
    int first = (t == 0) ? 1 : 0;
    for (int tag = 0; tag < 2; ++tag) {
      if (tag == 0)
        k_lstm_r<<<BB, 1024, 0, stream>>>(U, st_s, st_e, hbuf, cbuf, w_ih, w_hh, b_ih, b_hh,
                                          Wr[0], W1[0], b1[0], rcorr, ue);
      else
        k_re<<<BB, 1024, 0, stream>>>(U, st_s, ue, hbuf, Wr[1], W1[1], b1[1], rcorr);

      if (tierB)
        k_mgemm<0, 1><<<gg, 256, 0, stream>>>(nullptr, 0, 0, Uh, Ul,
            W1h[tag], W1l[tag], KA, rcorr, m1h, m1l, partial, W12[tag], 0);
      else
        k_mgemm<0, 0><<<gg, 256, 0, stream>>>(U, 400, 400, nullptr, nullptr,
            W1h[tag], W1l[tag], KA, rcorr, m1h, m1l, partial, W12[tag], 0);

      k_mgemm<1, 1><<<gg, 256, 0, stream>>>(nullptr, 0, 0, m1h, m1l,
          W2h[tag], W2l[tag], KB, b2[tag], nullptr, nullptr, partial, W12[tag], 14);

      k_reduce<<<BB, 256, 0, stream>>>(partial, b12[tag], dmask, span, tag, idxb, atgt);
      if (tag == 0)
        k_update<<<1, 64, 0, stream>>>(idxb, atgt, st_s, msb, out + 1, out, first);
      else
        k_update<<<1, 64, 0, stream>>>(idxb, atgt, st_e, meb, out + 1 + BB, out, first);
    }
  }
}